// Round 1
// baseline (926.545 us; speedup 1.0000x reference)
//
#include <hip/hip_runtime.h>
#include <cstdint>
#include <cstddef>

#define T_TOK 8192
#define D_DIM 1024
#define F_DIM 4096
#define E_NUM 8
#define CAP   2560
#define BKS   32

typedef __attribute__((ext_vector_type(8))) short bf16x8;
typedef __attribute__((ext_vector_type(4))) float f32x4;

typedef const __attribute__((address_space(1))) void* gas_ptr;
typedef __attribute__((address_space(3))) void* las_ptr;

__device__ __forceinline__ unsigned short f2bf(float f) {
  unsigned u = __float_as_uint(f);
  u += 0x7FFF + ((u >> 16) & 1);
  return (unsigned short)(u >> 16);
}

__device__ __forceinline__ float gelu_f(float x) {
  float u = 0.7978845608028654f * (x + 0.044715f * x * x * x);
  float t = 1.0f - 2.0f / (__expf(2.0f * u) + 1.0f);   // tanh(u)
  return 0.5f * x * (1.0f + t);
}

// ---------------- routing: logits (fp32), top-2, gates; also emit bf16 x ----
__global__ __launch_bounds__(256) void route_kernel(
    const float* __restrict__ x, const float* __restrict__ wr,
    unsigned short* __restrict__ xbf, int2* __restrict__ tokE,
    float2* __restrict__ tokG)
{
  int tid = threadIdx.x;
  int l = tid & 63;
  int w = tid >> 6;
  int t = blockIdx.x * 4 + w;
  const float4* xr = (const float4*)(x + (size_t)t * D_DIM);
  ushort4* xbr = (ushort4*)(xbf + (size_t)t * D_DIM);
  float acc[E_NUM];
#pragma unroll
  for (int e = 0; e < E_NUM; ++e) acc[e] = 0.f;
#pragma unroll
  for (int c = 0; c < D_DIM / 256; ++c) {
    float4 xv = xr[c * 64 + l];
    ushort4 bv;
    bv.x = f2bf(xv.x); bv.y = f2bf(xv.y); bv.z = f2bf(xv.z); bv.w = f2bf(xv.w);
    xbr[c * 64 + l] = bv;
#pragma unroll
    for (int e = 0; e < E_NUM; ++e) {
      float4 wv = ((const float4*)(wr + (size_t)e * D_DIM))[c * 64 + l];
      acc[e] += xv.x * wv.x + xv.y * wv.y + xv.z * wv.z + xv.w * wv.w;
    }
  }
#pragma unroll
  for (int e = 0; e < E_NUM; ++e) {
#pragma unroll
    for (int s = 32; s > 0; s >>= 1) acc[e] += __shfl_xor(acc[e], s);
  }
  if (l == 0) {
    int e1 = 0; float v1 = acc[0];
#pragma unroll
    for (int e = 1; e < E_NUM; ++e) if (acc[e] > v1) { v1 = acc[e]; e1 = e; }
    int e2 = -1; float v2 = -3.4e38f;
#pragma unroll
    for (int e = 0; e < E_NUM; ++e) if (e != e1 && acc[e] > v2) { v2 = acc[e]; e2 = e; }
    float s = __expf(v2 - v1);
    float g1 = 1.f / (1.f + s);
    tokE[t] = make_int2(e1, e2);
    tokG[t] = make_float2(g1, s * g1);
  }
}

// ---------------- capacity scan: token-order cumsum per expert --------------
__global__ __launch_bounds__(256) void scan_kernel(
    const int2* __restrict__ tokE, const float2* __restrict__ tokG,
    int* __restrict__ dispatch, float* __restrict__ sgate)
{
  int e = blockIdx.x;
  int tid = threadIdx.x;
  int l = tid & 63;
  int w = tid >> 6;
  __shared__ int wsum[4];
  int base = 0;
  for (int chunk = 0; chunk < T_TOK; chunk += 256) {
    int t = chunk + tid;
    int2 te = tokE[t];
    float2 tg = tokG[t];
    bool f1 = (te.x == e);
    bool f2 = (te.y == e);
    bool f = f1 || f2;
    unsigned long long m = __ballot(f);
    int rank = __popcll(m & ((1ull << l) - 1ull));
    if (l == 0) wsum[w] = __popcll(m);
    __syncthreads();
    int woff = 0;
#pragma unroll
    for (int i = 0; i < 4; ++i) if (i < w) woff += wsum[i];
    int tot = wsum[0] + wsum[1] + wsum[2] + wsum[3];
    int pos = base + woff + rank;
    if (f && pos < CAP) {
      dispatch[e * CAP + pos] = t;
      sgate[e * CAP + pos] = f1 ? tg.x : tg.y;
    }
    base += tot;
    __syncthreads();
  }
  int start = base < CAP ? base : CAP;
  for (int p = start + tid; p < CAP; p += 256) {
    dispatch[e * CAP + p] = T_TOK;
    sgate[e * CAP + p] = 0.f;
  }
}

// ---------------- transpose + fp32->bf16: (K,N) -> (N,K) --------------------
__global__ __launch_bounds__(256) void transpose_kernel(
    const float* __restrict__ src, unsigned short* __restrict__ dst,
    int K, int N)
{
  const float* s = src + (size_t)blockIdx.z * K * N;
  unsigned short* d = dst + (size_t)blockIdx.z * K * N;
  __shared__ float tile[32][33];
  int tx = threadIdx.x & 31;
  int ty = threadIdx.x >> 5;
  int n0 = blockIdx.x * 32;
  int k0 = blockIdx.y * 32;
#pragma unroll
  for (int i = 0; i < 4; ++i)
    tile[ty + i * 8][tx] = s[(size_t)(k0 + ty + i * 8) * N + n0 + tx];
  __syncthreads();
#pragma unroll
  for (int i = 0; i < 4; ++i)
    d[(size_t)(n0 + ty + i * 8) * K + k0 + tx] = f2bf(tile[tx][ty + i * 8]);
}

// ---------------- GEMM1: h = gelu(xg @ w1 + b1), h stored bf16 --------------
__global__ __launch_bounds__(256) void gemm1_kernel(
    const unsigned short* __restrict__ xbf,   // (T+1, D) bf16, row T zeroed
    const unsigned short* __restrict__ w1t,   // (F, D) bf16 per expert (stride)
    const float* __restrict__ b1,             // (E, F)
    const int* __restrict__ dispatch,         // (E, CAP)
    unsigned short* __restrict__ h,           // (CAP, F) bf16 per expert (stride)
    int e_base, size_t w1stride, size_t hstride)
{
  int e = e_base + blockIdx.z;
  const unsigned short* w1e = w1t + (size_t)blockIdx.z * w1stride;
  unsigned short* he = h + (size_t)blockIdx.z * hstride;
  int n0 = blockIdx.x * 128;
  int m0 = blockIdx.y * 128;
  int tid = threadIdx.x;
  int l = tid & 63;
  int wid = tid >> 6;
  int wm = wid >> 1, wn = wid & 1;
  int lrow = l & 15, lhi = l >> 4;

  __shared__ __align__(16) unsigned short As[2][128 * BKS];
  __shared__ __align__(16) unsigned short Bs[2][128 * BKS];

  int slot = tid & 3;
  const unsigned short* asrc[2];
  const unsigned short* bsrc[2];
#pragma unroll
  for (int i = 0; i < 2; ++i) {
    int row = i * 64 + (tid >> 2);
    int r = m0 + row;
    int tok = (r < CAP) ? dispatch[e * CAP + r] : T_TOK;
    asrc[i] = xbf + (size_t)tok * D_DIM + slot * 8;
    bsrc[i] = w1e + (size_t)(n0 + row) * D_DIM + slot * 8;
  }

  f32x4 acc[4][4];
#pragma unroll
  for (int m = 0; m < 4; ++m)
#pragma unroll
    for (int n = 0; n < 4; ++n) acc[m][n] = (f32x4){0.f, 0.f, 0.f, 0.f};

  const int NK = D_DIM / BKS;
#pragma unroll
  for (int i = 0; i < 2; ++i) {
    __builtin_amdgcn_global_load_lds((gas_ptr)(asrc[i]),
        (las_ptr)&As[0][(i * 256 + wid * 64) * 8], 16, 0, 0);
    __builtin_amdgcn_global_load_lds((gas_ptr)(bsrc[i]),
        (las_ptr)&Bs[0][(i * 256 + wid * 64) * 8], 16, 0, 0);
  }
  __syncthreads();

  for (int t = 0; t < NK; ++t) {
    int cur = t & 1;
    if (t + 1 < NK) {
      int nxt = cur ^ 1;
      int k0 = (t + 1) * BKS;
#pragma unroll
      for (int i = 0; i < 2; ++i) {
        __builtin_amdgcn_global_load_lds((gas_ptr)(asrc[i] + k0),
            (las_ptr)&As[nxt][(i * 256 + wid * 64) * 8], 16, 0, 0);
        __builtin_amdgcn_global_load_lds((gas_ptr)(bsrc[i] + k0),
            (las_ptr)&Bs[nxt][(i * 256 + wid * 64) * 8], 16, 0, 0);
      }
    }
    bf16x8 af[4], bfr[4];
#pragma unroll
    for (int m = 0; m < 4; ++m) {
      int row = wm * 64 + m * 16 + lrow;
      af[m] = *(const bf16x8*)&As[cur][row * BKS + lhi * 8];
    }
#pragma unroll
    for (int n = 0; n < 4; ++n) {
      int col = wn * 64 + n * 16 + lrow;
      bfr[n] = *(const bf16x8*)&Bs[cur][col * BKS + lhi * 8];
    }
#pragma unroll
    for (int m = 0; m < 4; ++m)
#pragma unroll
      for (int n = 0; n < 4; ++n)
        acc[m][n] = __builtin_amdgcn_mfma_f32_16x16x32_bf16(af[m], bfr[n], acc[m][n], 0, 0, 0);
    __syncthreads();
  }

  int colg[4]; float b1v[4];
#pragma unroll
  for (int n = 0; n < 4; ++n) {
    colg[n] = n0 + wn * 64 + n * 16 + lrow;
    b1v[n] = b1[e * F_DIM + colg[n]];
  }
#pragma unroll
  for (int m = 0; m < 4; ++m) {
    int rb = m0 + wm * 64 + m * 16 + lhi * 4;
#pragma unroll
    for (int j = 0; j < 4; ++j) {
      int r = rb + j;
      if (r < CAP) {
        unsigned short* hr = he + (size_t)r * F_DIM;
#pragma unroll
        for (int n = 0; n < 4; ++n) {
          float v = acc[m][n][j] + b1v[n];
          hr[colg[n]] = f2bf(gelu_f(v));
        }
      }
    }
  }
}

// ---------------- GEMM2: y = h @ w2 + b2; out[tok] += gate*y (atomic) -------
__global__ __launch_bounds__(256) void gemm2_kernel(
    const unsigned short* __restrict__ h,     // (CAP, F) bf16 per expert
    const unsigned short* __restrict__ w2t,   // (D, F) bf16 per expert
    const float* __restrict__ b2,             // (E, D)
    const int* __restrict__ dispatch,
    const float* __restrict__ sgate,
    float* __restrict__ out,                  // (T, D) fp32, zero-initialized
    int e_base, size_t w2stride, size_t hstride)
{
  int e = e_base + blockIdx.z;
  const unsigned short* he = h + (size_t)blockIdx.z * hstride;
  const unsigned short* w2e = w2t + (size_t)blockIdx.z * w2stride;
  int n0 = blockIdx.x * 128;
  int m0 = blockIdx.y * 128;
  int tid = threadIdx.x;
  int l = tid & 63;
  int wid = tid >> 6;
  int wm = wid >> 1, wn = wid & 1;
  int lrow = l & 15, lhi = l >> 4;

  __shared__ __align__(16) unsigned short As[2][128 * BKS];
  __shared__ __align__(16) unsigned short Bs[2][128 * BKS];

  int slot = tid & 3;
  const unsigned short* asrc[2];
  const unsigned short* bsrc[2];
#pragma unroll
  for (int i = 0; i < 2; ++i) {
    int row = i * 64 + (tid >> 2);
    int r = m0 + row; if (r >= CAP) r = CAP - 1;
    asrc[i] = he + (size_t)r * F_DIM + slot * 8;
    bsrc[i] = w2e + (size_t)(n0 + row) * F_DIM + slot * 8;
  }

  f32x4 acc[4][4];
#pragma unroll
  for (int m = 0; m < 4; ++m)
#pragma unroll
    for (int n = 0; n < 4; ++n) acc[m][n] = (f32x4){0.f, 0.f, 0.f, 0.f};

  const int NK = F_DIM / BKS;
#pragma unroll
  for (int i = 0; i < 2; ++i) {
    __builtin_amdgcn_global_load_lds((gas_ptr)(asrc[i]),
        (las_ptr)&As[0][(i * 256 + wid * 64) * 8], 16, 0, 0);
    __builtin_amdgcn_global_load_lds((gas_ptr)(bsrc[i]),
        (las_ptr)&Bs[0][(i * 256 + wid * 64) * 8], 16, 0, 0);
  }
  __syncthreads();

  for (int t = 0; t < NK; ++t) {
    int cur = t & 1;
    if (t + 1 < NK) {
      int nxt = cur ^ 1;
      int k0 = (t + 1) * BKS;
#pragma unroll
      for (int i = 0; i < 2; ++i) {
        __builtin_amdgcn_global_load_lds((gas_ptr)(asrc[i] + k0),
            (las_ptr)&As[nxt][(i * 256 + wid * 64) * 8], 16, 0, 0);
        __builtin_amdgcn_global_load_lds((gas_ptr)(bsrc[i] + k0),
            (las_ptr)&Bs[nxt][(i * 256 + wid * 64) * 8], 16, 0, 0);
      }
    }
    bf16x8 af[4], bfr[4];
#pragma unroll
    for (int m = 0; m < 4; ++m) {
      int row = wm * 64 + m * 16 + lrow;
      af[m] = *(const bf16x8*)&As[cur][row * BKS + lhi * 8];
    }
#pragma unroll
    for (int n = 0; n < 4; ++n) {
      int col = wn * 64 + n * 16 + lrow;
      bfr[n] = *(const bf16x8*)&Bs[cur][col * BKS + lhi * 8];
    }
#pragma unroll
    for (int m = 0; m < 4; ++m)
#pragma unroll
      for (int n = 0; n < 4; ++n)
        acc[m][n] = __builtin_amdgcn_mfma_f32_16x16x32_bf16(af[m], bfr[n], acc[m][n], 0, 0, 0);
    __syncthreads();
  }

  int colg[4]; float b2v[4];
#pragma unroll
  for (int n = 0; n < 4; ++n) {
    colg[n] = n0 + wn * 64 + n * 16 + lrow;
    b2v[n] = b2[e * D_DIM + colg[n]];
  }
#pragma unroll
  for (int m = 0; m < 4; ++m) {
    int rb = m0 + wm * 64 + m * 16 + lhi * 4;
#pragma unroll
    for (int j = 0; j < 4; ++j) {
      int r = rb + j;
      if (r < CAP) {
        int tok = dispatch[e * CAP + r];
        if (tok < T_TOK) {
          float g = sgate[e * CAP + r];
          float* orow = out + (size_t)tok * D_DIM;
#pragma unroll
          for (int n = 0; n < 4; ++n)
            atomicAdd(&orow[colg[n]], g * (acc[m][n][j] + b2v[n]));
        }
      }
    }
  }
}

// ---------------- host-side launch ------------------------------------------
extern "C" void kernel_launch(void* const* d_in, const int* in_sizes, int n_in,
                              void* d_out, int out_size, void* d_ws, size_t ws_size,
                              hipStream_t stream) {
  const float* x  = (const float*)d_in[0];
  const float* wr = (const float*)d_in[1];
  const float* w1 = (const float*)d_in[2];
  const float* b1 = (const float*)d_in[3];
  const float* w2 = (const float*)d_in[4];
  const float* b2 = (const float*)d_in[5];
  float* out = (float*)d_out;

  char* ws = (char*)d_ws;
  size_t off = 0;
  auto alloc = [&](size_t bytes) -> void* {
    off = (off + 255) & ~(size_t)255;
    void* p = ws + off;
    off += bytes;
    return p;
  };
  int*   dispatch = (int*)alloc((size_t)E_NUM * CAP * 4);
  float* sgate    = (float*)alloc((size_t)E_NUM * CAP * 4);
  int2*  tokE     = (int2*)alloc((size_t)T_TOK * 8);
  float2* tokG    = (float2*)alloc((size_t)T_TOK * 8);
  unsigned short* xbf = (unsigned short*)alloc((size_t)(T_TOK + 1) * D_DIM * 2);

  const size_t wsz = (size_t)D_DIM * F_DIM * 2;  // one expert weight, bf16 bytes
  const size_t hsz = (size_t)CAP * F_DIM * 2;    // one expert h, bf16 bytes
  size_t remain = ws_size > off ? ws_size - off : 0;
  bool tierA = remain >= (size_t)E_NUM * (2 * wsz + hsz) + (size_t)(1 << 16);

  hipMemsetAsync(out, 0, (size_t)T_TOK * D_DIM * 4, stream);
  hipMemsetAsync(xbf + (size_t)T_TOK * D_DIM, 0, D_DIM * 2, stream);
  route_kernel<<<T_TOK / 4, 256, 0, stream>>>(x, wr, xbf, tokE, tokG);
  scan_kernel<<<E_NUM, 256, 0, stream>>>(tokE, tokG, dispatch, sgate);

  if (tierA) {
    unsigned short* w1t = (unsigned short*)alloc((size_t)E_NUM * wsz);
    unsigned short* w2t = (unsigned short*)alloc((size_t)E_NUM * wsz);
    unsigned short* hb  = (unsigned short*)alloc((size_t)E_NUM * hsz);
    transpose_kernel<<<dim3(F_DIM / 32, D_DIM / 32, E_NUM), 256, 0, stream>>>(w1, w1t, D_DIM, F_DIM);
    transpose_kernel<<<dim3(D_DIM / 32, F_DIM / 32, E_NUM), 256, 0, stream>>>(w2, w2t, F_DIM, D_DIM);
    gemm1_kernel<<<dim3(F_DIM / 128, (CAP + 127) / 128, E_NUM), 256, 0, stream>>>(
        xbf, w1t, b1, dispatch, hb, 0, wsz / 2, hsz / 2);
    gemm2_kernel<<<dim3(D_DIM / 128, (CAP + 127) / 128, E_NUM), 256, 0, stream>>>(
        hb, w2t, b2, dispatch, sgate, out, 0, wsz / 2, hsz / 2);
  } else {
    unsigned short* w1t = (unsigned short*)alloc(wsz);
    unsigned short* w2t = (unsigned short*)alloc(wsz);
    unsigned short* hb  = (unsigned short*)alloc(hsz);
    for (int e = 0; e < E_NUM; ++e) {
      transpose_kernel<<<dim3(F_DIM / 32, D_DIM / 32, 1), 256, 0, stream>>>(
          w1 + (size_t)e * D_DIM * F_DIM, w1t, D_DIM, F_DIM);
      gemm1_kernel<<<dim3(F_DIM / 128, (CAP + 127) / 128, 1), 256, 0, stream>>>(
          xbf, w1t, b1, dispatch, hb, e, 0, 0);
      transpose_kernel<<<dim3(D_DIM / 32, F_DIM / 32, 1), 256, 0, stream>>>(
          w2 + (size_t)e * D_DIM * F_DIM, w2t, F_DIM, D_DIM);
      gemm2_kernel<<<dim3(D_DIM / 128, (CAP + 127) / 128, 1), 256, 0, stream>>>(
          hb, w2t, b2, dispatch, sgate, out, e, 0, 0);
    }
  }
}

// Round 2
// 874.029 us; speedup vs baseline: 1.0601x; 1.0601x over previous
//
#include <hip/hip_runtime.h>
#include <cstdint>
#include <cstddef>

#define T_TOK 8192
#define D_DIM 1024
#define F_DIM 4096
#define E_NUM 8
#define CAP   2560
#define BKS   32
#define MYB   20   // CAP / 128

typedef __attribute__((ext_vector_type(8))) short bf16x8;
typedef __attribute__((ext_vector_type(4))) float f32x4;

typedef const __attribute__((address_space(1))) void* gas_ptr;
typedef __attribute__((address_space(3))) void* las_ptr;

__device__ __forceinline__ unsigned short f2bf(float f) {
  unsigned u = __float_as_uint(f);
  u += 0x7FFF + ((u >> 16) & 1);
  return (unsigned short)(u >> 16);
}

__device__ __forceinline__ float gelu_f(float x) {
  float u = 0.7978845608028654f * (x + 0.044715f * x * x * x);
  float t = 1.0f - 2.0f / (__expf(2.0f * u) + 1.0f);   // tanh(u)
  return 0.5f * x * (1.0f + t);
}

// XCD-chunked bijective swizzle (nwg % 8 == 0 guaranteed by our launches).
__device__ __forceinline__ int xcd_swizzle(int bid, int nwg) {
  int q = nwg >> 3;
  return (bid & 7) * q + (bid >> 3);
}

// ---------------- routing: logits (fp32), top-2, gates; also emit bf16 x ----
__global__ __launch_bounds__(256) void route_kernel(
    const float* __restrict__ x, const float* __restrict__ wr,
    unsigned short* __restrict__ xbf, int2* __restrict__ tokE,
    float2* __restrict__ tokG)
{
  int tid = threadIdx.x;
  int l = tid & 63;
  int w = tid >> 6;
  int t = blockIdx.x * 4 + w;
  const float4* xr = (const float4*)(x + (size_t)t * D_DIM);
  ushort4* xbr = (ushort4*)(xbf + (size_t)t * D_DIM);
  float acc[E_NUM];
#pragma unroll
  for (int e = 0; e < E_NUM; ++e) acc[e] = 0.f;
#pragma unroll
  for (int c = 0; c < D_DIM / 256; ++c) {
    float4 xv = xr[c * 64 + l];
    ushort4 bv;
    bv.x = f2bf(xv.x); bv.y = f2bf(xv.y); bv.z = f2bf(xv.z); bv.w = f2bf(xv.w);
    xbr[c * 64 + l] = bv;
#pragma unroll
    for (int e = 0; e < E_NUM; ++e) {
      float4 wv = ((const float4*)(wr + (size_t)e * D_DIM))[c * 64 + l];
      acc[e] += xv.x * wv.x + xv.y * wv.y + xv.z * wv.z + xv.w * wv.w;
    }
  }
#pragma unroll
  for (int e = 0; e < E_NUM; ++e) {
#pragma unroll
    for (int s = 32; s > 0; s >>= 1) acc[e] += __shfl_xor(acc[e], s);
  }
  if (l == 0) {
    int e1 = 0; float v1 = acc[0];
#pragma unroll
    for (int e = 1; e < E_NUM; ++e) if (acc[e] > v1) { v1 = acc[e]; e1 = e; }
    int e2 = -1; float v2 = -3.4e38f;
#pragma unroll
    for (int e = 0; e < E_NUM; ++e) if (e != e1 && acc[e] > v2) { v2 = acc[e]; e2 = e; }
    float s = __expf(v2 - v1);
    float g1 = 1.f / (1.f + s);
    tokE[t] = make_int2(e1, e2);
    tokG[t] = make_float2(g1, s * g1);
  }
}

// ---------------- capacity scan: token-order cumsum per expert --------------
__global__ __launch_bounds__(256) void scan_kernel(
    const int2* __restrict__ tokE, const float2* __restrict__ tokG,
    int* __restrict__ dispatch, float* __restrict__ sgate)
{
  int e = blockIdx.x;
  int tid = threadIdx.x;
  int l = tid & 63;
  int w = tid >> 6;
  __shared__ int wsum[4];
  int base = 0;
  for (int chunk = 0; chunk < T_TOK; chunk += 256) {
    int t = chunk + tid;
    int2 te = tokE[t];
    float2 tg = tokG[t];
    bool f1 = (te.x == e);
    bool f2 = (te.y == e);
    bool f = f1 || f2;
    unsigned long long m = __ballot(f);
    int rank = __popcll(m & ((1ull << l) - 1ull));
    if (l == 0) wsum[w] = __popcll(m);
    __syncthreads();
    int woff = 0;
#pragma unroll
    for (int i = 0; i < 4; ++i) if (i < w) woff += wsum[i];
    int tot = wsum[0] + wsum[1] + wsum[2] + wsum[3];
    int pos = base + woff + rank;
    if (f && pos < CAP) {
      dispatch[e * CAP + pos] = t;
      sgate[e * CAP + pos] = f1 ? tg.x : tg.y;
    }
    base += tot;
    __syncthreads();
  }
  int start = base < CAP ? base : CAP;
  for (int p = start + tid; p < CAP; p += 256) {
    dispatch[e * CAP + p] = T_TOK;
    sgate[e * CAP + p] = 0.f;
  }
}

// ---------------- transpose + fp32->bf16: (K,N) -> (N,K) --------------------
__global__ __launch_bounds__(256) void transpose_kernel(
    const float* __restrict__ src, unsigned short* __restrict__ dst,
    int K, int N)
{
  const float* s = src + (size_t)blockIdx.z * K * N;
  unsigned short* d = dst + (size_t)blockIdx.z * K * N;
  __shared__ float tile[32][33];
  int tx = threadIdx.x & 31;
  int ty = threadIdx.x >> 5;
  int n0 = blockIdx.x * 32;
  int k0 = blockIdx.y * 32;
#pragma unroll
  for (int i = 0; i < 4; ++i)
    tile[ty + i * 8][tx] = s[(size_t)(k0 + ty + i * 8) * N + n0 + tx];
  __syncthreads();
#pragma unroll
  for (int i = 0; i < 4; ++i)
    d[(size_t)(n0 + ty + i * 8) * K + k0 + tx] = f2bf(tile[tx][ty + i * 8]);
}

// ---------------- GEMM1: h = gelu(xg @ w1 + b1), h stored bf16 --------------
// 1D grid, XCD-chunked swizzle, panel-major (e, nx) with M fastest.
#define G1_NXB (F_DIM / 128)   // 32
__global__ __launch_bounds__(256, 4) void gemm1_kernel(
    const unsigned short* __restrict__ xbf,   // (T+1, D) bf16, row T zeroed
    const unsigned short* __restrict__ w1t,   // (F, D) bf16 per expert (stride)
    const float* __restrict__ b1,             // (E, F)
    const int* __restrict__ dispatch,         // (E, CAP)
    unsigned short* __restrict__ h,           // (CAP, F) bf16 per expert (stride)
    int e_base, size_t w1stride, size_t hstride)
{
  int wg = xcd_swizzle(blockIdx.x, gridDim.x);
  int my = wg % MYB;
  int p  = wg / MYB;
  int nx = p % G1_NXB;
  int ez = p / G1_NXB;
  int e = e_base + ez;
  const unsigned short* w1e = w1t + (size_t)ez * w1stride;
  unsigned short* he = h + (size_t)ez * hstride;
  int n0 = nx * 128;
  int m0 = my * 128;
  int tid = threadIdx.x;
  int l = tid & 63;
  int wid = tid >> 6;
  int wm = wid >> 1, wn = wid & 1;
  int lrow = l & 15, lhi = l >> 4;

  __shared__ __align__(16) unsigned short As[2][128 * BKS];
  __shared__ __align__(16) unsigned short Bs[2][128 * BKS];

  int slot = tid & 3;
  const unsigned short* asrc[2];
  const unsigned short* bsrc[2];
#pragma unroll
  for (int i = 0; i < 2; ++i) {
    int row = i * 64 + (tid >> 2);
    int r = m0 + row;
    int tok = (r < CAP) ? dispatch[e * CAP + r] : T_TOK;
    asrc[i] = xbf + (size_t)tok * D_DIM + slot * 8;
    bsrc[i] = w1e + (size_t)(n0 + row) * D_DIM + slot * 8;
  }

  f32x4 acc[4][4];
#pragma unroll
  for (int m = 0; m < 4; ++m)
#pragma unroll
    for (int n = 0; n < 4; ++n) acc[m][n] = (f32x4){0.f, 0.f, 0.f, 0.f};

  const int NK = D_DIM / BKS;
#pragma unroll
  for (int i = 0; i < 2; ++i) {
    __builtin_amdgcn_global_load_lds((gas_ptr)(asrc[i]),
        (las_ptr)&As[0][(i * 256 + wid * 64) * 8], 16, 0, 0);
    __builtin_amdgcn_global_load_lds((gas_ptr)(bsrc[i]),
        (las_ptr)&Bs[0][(i * 256 + wid * 64) * 8], 16, 0, 0);
  }
  __syncthreads();

  for (int t = 0; t < NK; ++t) {
    int cur = t & 1;
    if (t + 1 < NK) {
      int nxt = cur ^ 1;
      int k0 = (t + 1) * BKS;
#pragma unroll
      for (int i = 0; i < 2; ++i) {
        __builtin_amdgcn_global_load_lds((gas_ptr)(asrc[i] + k0),
            (las_ptr)&As[nxt][(i * 256 + wid * 64) * 8], 16, 0, 0);
        __builtin_amdgcn_global_load_lds((gas_ptr)(bsrc[i] + k0),
            (las_ptr)&Bs[nxt][(i * 256 + wid * 64) * 8], 16, 0, 0);
      }
    }
    bf16x8 af[4], bfr[4];
#pragma unroll
    for (int m = 0; m < 4; ++m) {
      int row = wm * 64 + m * 16 + lrow;
      af[m] = *(const bf16x8*)&As[cur][row * BKS + lhi * 8];
    }
#pragma unroll
    for (int n = 0; n < 4; ++n) {
      int col = wn * 64 + n * 16 + lrow;
      bfr[n] = *(const bf16x8*)&Bs[cur][col * BKS + lhi * 8];
    }
#pragma unroll
    for (int m = 0; m < 4; ++m)
#pragma unroll
      for (int n = 0; n < 4; ++n)
        acc[m][n] = __builtin_amdgcn_mfma_f32_16x16x32_bf16(af[m], bfr[n], acc[m][n], 0, 0, 0);
    __syncthreads();
  }

  int colg[4]; float b1v[4];
#pragma unroll
  for (int n = 0; n < 4; ++n) {
    colg[n] = n0 + wn * 64 + n * 16 + lrow;
    b1v[n] = b1[e * F_DIM + colg[n]];
  }
#pragma unroll
  for (int m = 0; m < 4; ++m) {
    int rb = m0 + wm * 64 + m * 16 + lhi * 4;
#pragma unroll
    for (int j = 0; j < 4; ++j) {
      int r = rb + j;
      if (r < CAP) {
        unsigned short* hr = he + (size_t)r * F_DIM;
#pragma unroll
        for (int n = 0; n < 4; ++n) {
          float v = acc[m][n][j] + b1v[n];
          hr[colg[n]] = f2bf(gelu_f(v));
        }
      }
    }
  }
}

// ---------------- GEMM2: y = h @ w2 + b2; out[tok] += gate*y (atomic) -------
#define G2_NXB (D_DIM / 128)   // 8
__global__ __launch_bounds__(256, 4) void gemm2_kernel(
    const unsigned short* __restrict__ h,     // (CAP, F) bf16 per expert
    const unsigned short* __restrict__ w2t,   // (D, F) bf16 per expert
    const float* __restrict__ b2,             // (E, D)
    const int* __restrict__ dispatch,
    const float* __restrict__ sgate,
    float* __restrict__ out,                  // (T, D) fp32, zero-initialized
    int e_base, size_t w2stride, size_t hstride)
{
  int wg = xcd_swizzle(blockIdx.x, gridDim.x);
  int my = wg % MYB;
  int p  = wg / MYB;
  int nx = p % G2_NXB;
  int ez = p / G2_NXB;
  int e = e_base + ez;
  const unsigned short* he = h + (size_t)ez * hstride;
  const unsigned short* w2e = w2t + (size_t)ez * w2stride;
  int n0 = nx * 128;
  int m0 = my * 128;
  int tid = threadIdx.x;
  int l = tid & 63;
  int wid = tid >> 6;
  int wm = wid >> 1, wn = wid & 1;
  int lrow = l & 15, lhi = l >> 4;

  __shared__ __align__(16) unsigned short As[2][128 * BKS];
  __shared__ __align__(16) unsigned short Bs[2][128 * BKS];

  int slot = tid & 3;
  const unsigned short* asrc[2];
  const unsigned short* bsrc[2];
#pragma unroll
  for (int i = 0; i < 2; ++i) {
    int row = i * 64 + (tid >> 2);
    int r = m0 + row; if (r >= CAP) r = CAP - 1;
    asrc[i] = he + (size_t)r * F_DIM + slot * 8;
    bsrc[i] = w2e + (size_t)(n0 + row) * F_DIM + slot * 8;
  }

  f32x4 acc[4][4];
#pragma unroll
  for (int m = 0; m < 4; ++m)
#pragma unroll
    for (int n = 0; n < 4; ++n) acc[m][n] = (f32x4){0.f, 0.f, 0.f, 0.f};

  const int NK = F_DIM / BKS;
#pragma unroll
  for (int i = 0; i < 2; ++i) {
    __builtin_amdgcn_global_load_lds((gas_ptr)(asrc[i]),
        (las_ptr)&As[0][(i * 256 + wid * 64) * 8], 16, 0, 0);
    __builtin_amdgcn_global_load_lds((gas_ptr)(bsrc[i]),
        (las_ptr)&Bs[0][(i * 256 + wid * 64) * 8], 16, 0, 0);
  }
  __syncthreads();

  for (int t = 0; t < NK; ++t) {
    int cur = t & 1;
    if (t + 1 < NK) {
      int nxt = cur ^ 1;
      int k0 = (t + 1) * BKS;
#pragma unroll
      for (int i = 0; i < 2; ++i) {
        __builtin_amdgcn_global_load_lds((gas_ptr)(asrc[i] + k0),
            (las_ptr)&As[nxt][(i * 256 + wid * 64) * 8], 16, 0, 0);
        __builtin_amdgcn_global_load_lds((gas_ptr)(bsrc[i] + k0),
            (las_ptr)&Bs[nxt][(i * 256 + wid * 64) * 8], 16, 0, 0);
      }
    }
    bf16x8 af[4], bfr[4];
#pragma unroll
    for (int m = 0; m < 4; ++m) {
      int row = wm * 64 + m * 16 + lrow;
      af[m] = *(const bf16x8*)&As[cur][row * BKS + lhi * 8];
    }
#pragma unroll
    for (int n = 0; n < 4; ++n) {
      int col = wn * 64 + n * 16 + lrow;
      bfr[n] = *(const bf16x8*)&Bs[cur][col * BKS + lhi * 8];
    }
#pragma unroll
    for (int m = 0; m < 4; ++m)
#pragma unroll
      for (int n = 0; n < 4; ++n)
        acc[m][n] = __builtin_amdgcn_mfma_f32_16x16x32_bf16(af[m], bfr[n], acc[m][n], 0, 0, 0);
    __syncthreads();
  }

  int colg[4]; float b2v[4];
#pragma unroll
  for (int n = 0; n < 4; ++n) {
    colg[n] = n0 + wn * 64 + n * 16 + lrow;
    b2v[n] = b2[e * D_DIM + colg[n]];
  }
#pragma unroll
  for (int m = 0; m < 4; ++m) {
    int rb = m0 + wm * 64 + m * 16 + lhi * 4;
#pragma unroll
    for (int j = 0; j < 4; ++j) {
      int r = rb + j;
      if (r < CAP) {
        int tok = dispatch[e * CAP + r];
        if (tok < T_TOK) {
          float g = sgate[e * CAP + r];
          float* orow = out + (size_t)tok * D_DIM;
#pragma unroll
          for (int n = 0; n < 4; ++n)
            atomicAdd(&orow[colg[n]], g * (acc[m][n][j] + b2v[n]));
        }
      }
    }
  }
}

// ---------------- host-side launch ------------------------------------------
extern "C" void kernel_launch(void* const* d_in, const int* in_sizes, int n_in,
                              void* d_out, int out_size, void* d_ws, size_t ws_size,
                              hipStream_t stream) {
  const float* x  = (const float*)d_in[0];
  const float* wr = (const float*)d_in[1];
  const float* w1 = (const float*)d_in[2];
  const float* b1 = (const float*)d_in[3];
  const float* w2 = (const float*)d_in[4];
  const float* b2 = (const float*)d_in[5];
  float* out = (float*)d_out;

  char* ws = (char*)d_ws;
  size_t off = 0;
  auto alloc = [&](size_t bytes) -> void* {
    off = (off + 255) & ~(size_t)255;
    void* p = ws + off;
    off += bytes;
    return p;
  };
  int*   dispatch = (int*)alloc((size_t)E_NUM * CAP * 4);
  float* sgate    = (float*)alloc((size_t)E_NUM * CAP * 4);
  int2*  tokE     = (int2*)alloc((size_t)T_TOK * 8);
  float2* tokG    = (float2*)alloc((size_t)T_TOK * 8);
  unsigned short* xbf = (unsigned short*)alloc((size_t)(T_TOK + 1) * D_DIM * 2);

  const size_t wsz = (size_t)D_DIM * F_DIM * 2;  // one expert weight, bf16 bytes
  const size_t hsz = (size_t)CAP * F_DIM * 2;    // one expert h, bf16 bytes
  size_t remain = ws_size > off ? ws_size - off : 0;
  bool tierA = remain >= (size_t)E_NUM * (2 * wsz + hsz) + (size_t)(1 << 16);

  hipMemsetAsync(out, 0, (size_t)T_TOK * D_DIM * 4, stream);
  hipMemsetAsync(xbf + (size_t)T_TOK * D_DIM, 0, D_DIM * 2, stream);
  route_kernel<<<T_TOK / 4, 256, 0, stream>>>(x, wr, xbf, tokE, tokG);
  scan_kernel<<<E_NUM, 256, 0, stream>>>(tokE, tokG, dispatch, sgate);

  if (tierA) {
    unsigned short* w1t = (unsigned short*)alloc((size_t)E_NUM * wsz);
    unsigned short* w2t = (unsigned short*)alloc((size_t)E_NUM * wsz);
    unsigned short* hb  = (unsigned short*)alloc((size_t)E_NUM * hsz);
    transpose_kernel<<<dim3(F_DIM / 32, D_DIM / 32, E_NUM), 256, 0, stream>>>(w1, w1t, D_DIM, F_DIM);
    transpose_kernel<<<dim3(D_DIM / 32, F_DIM / 32, E_NUM), 256, 0, stream>>>(w2, w2t, F_DIM, D_DIM);
    gemm1_kernel<<<dim3(G1_NXB * MYB * E_NUM), 256, 0, stream>>>(
        xbf, w1t, b1, dispatch, hb, 0, wsz / 2, hsz / 2);
    gemm2_kernel<<<dim3(G2_NXB * MYB * E_NUM), 256, 0, stream>>>(
        hb, w2t, b2, dispatch, sgate, out, 0, wsz / 2, hsz / 2);
  } else {
    unsigned short* w1t = (unsigned short*)alloc(wsz);
    unsigned short* w2t = (unsigned short*)alloc(wsz);
    unsigned short* hb  = (unsigned short*)alloc(hsz);
    for (int e = 0; e < E_NUM; ++e) {
      transpose_kernel<<<dim3(F_DIM / 32, D_DIM / 32, 1), 256, 0, stream>>>(
          w1 + (size_t)e * D_DIM * F_DIM, w1t, D_DIM, F_DIM);
      gemm1_kernel<<<dim3(G1_NXB * MYB), 256, 0, stream>>>(
          xbf, w1t, b1, dispatch, hb, e, 0, 0);
      transpose_kernel<<<dim3(D_DIM / 32, F_DIM / 32, 1), 256, 0, stream>>>(
          w2 + (size_t)e * D_DIM * F_DIM, w2t, F_DIM, D_DIM);
      gemm2_kernel<<<dim3(G2_NXB * MYB), 256, 0, stream>>>(
          hb, w2t, b2, dispatch, sgate, out, e, 0, 0);
    }
  }
}

// Round 4
// 774.038 us; speedup vs baseline: 1.1970x; 1.1292x over previous
//
#include <hip/hip_runtime.h>
#include <cstdint>
#include <cstddef>

#define T_TOK 8192
#define D_DIM 1024
#define F_DIM 4096
#define E_NUM 8
#define CAP   2560
#define BKS   32
#define MYB   20            // CAP / 128
#define LDSB  16384         // bytes per pipeline buffer (A 8KB + B 8KB)

typedef __attribute__((ext_vector_type(8))) short bf16x8;
typedef __attribute__((ext_vector_type(8))) unsigned short u16x8;
typedef __attribute__((ext_vector_type(4))) float f32x4;

typedef const __attribute__((address_space(1))) void* gas_ptr;
typedef __attribute__((address_space(3))) void* las_ptr;

__device__ __forceinline__ unsigned short f2bf(float f) {
  unsigned u = __float_as_uint(f);
  u += 0x7FFF + ((u >> 16) & 1);
  return (unsigned short)(u >> 16);
}

__device__ __forceinline__ float gelu_f(float x) {
  float u = 0.7978845608028654f * (x + 0.044715f * x * x * x);
  float t = 1.0f - 2.0f / (__expf(2.0f * u) + 1.0f);   // tanh(u)
  return 0.5f * x * (1.0f + t);
}

// XCD-chunked bijective swizzle (nwg % 8 == 0 for all our launches).
__device__ __forceinline__ int xcd_swizzle(int bid, int nwg) {
  int q = nwg >> 3;
  return (bid & 7) * q + (bid >> 3);
}

// counted-vmcnt pipeline barrier: never drains to 0 in steady state
#define PIPE_BAR4() asm volatile("s_waitcnt vmcnt(4)\n\ts_barrier" ::: "memory")
#define PIPE_BAR0() asm volatile("s_waitcnt vmcnt(0)\n\ts_barrier" ::: "memory")

// ---------------- routing: logits (fp32), top-2, gates; also emit bf16 x ----
__global__ __launch_bounds__(256) void route_kernel(
    const float* __restrict__ x, const float* __restrict__ wr,
    unsigned short* __restrict__ xbf, int2* __restrict__ tokE,
    float2* __restrict__ tokG)
{
  int tid = threadIdx.x;
  int l = tid & 63;
  int w = tid >> 6;
  int t = blockIdx.x * 4 + w;
  const float4* xr = (const float4*)(x + (size_t)t * D_DIM);
  ushort4* xbr = (ushort4*)(xbf + (size_t)t * D_DIM);
  float acc[E_NUM];
#pragma unroll
  for (int e = 0; e < E_NUM; ++e) acc[e] = 0.f;
#pragma unroll
  for (int c = 0; c < D_DIM / 256; ++c) {
    float4 xv = xr[c * 64 + l];
    ushort4 bv;
    bv.x = f2bf(xv.x); bv.y = f2bf(xv.y); bv.z = f2bf(xv.z); bv.w = f2bf(xv.w);
    xbr[c * 64 + l] = bv;
#pragma unroll
    for (int e = 0; e < E_NUM; ++e) {
      float4 wv = ((const float4*)(wr + (size_t)e * D_DIM))[c * 64 + l];
      acc[e] += xv.x * wv.x + xv.y * wv.y + xv.z * wv.z + xv.w * wv.w;
    }
  }
#pragma unroll
  for (int e = 0; e < E_NUM; ++e) {
#pragma unroll
    for (int s = 32; s > 0; s >>= 1) acc[e] += __shfl_xor(acc[e], s);
  }
  if (l == 0) {
    int e1 = 0; float v1 = acc[0];
#pragma unroll
    for (int e = 1; e < E_NUM; ++e) if (acc[e] > v1) { v1 = acc[e]; e1 = e; }
    int e2 = -1; float v2 = -3.4e38f;
#pragma unroll
    for (int e = 0; e < E_NUM; ++e) if (e != e1 && acc[e] > v2) { v2 = acc[e]; e2 = e; }
    float s = __expf(v2 - v1);
    float g1 = 1.f / (1.f + s);
    tokE[t] = make_int2(e1, e2);
    tokG[t] = make_float2(g1, s * g1);
  }
}

// ---------------- capacity scan: token-order cumsum per expert --------------
__global__ __launch_bounds__(256) void scan_kernel(
    const int2* __restrict__ tokE, const float2* __restrict__ tokG,
    int* __restrict__ dispatch, float* __restrict__ sgate, int* __restrict__ cnt)
{
  int e = blockIdx.x;
  int tid = threadIdx.x;
  int l = tid & 63;
  int w = tid >> 6;
  __shared__ int wsum[4];
  int base = 0;
  for (int chunk = 0; chunk < T_TOK; chunk += 256) {
    int t = chunk + tid;
    int2 te = tokE[t];
    float2 tg = tokG[t];
    bool f1 = (te.x == e);
    bool f2 = (te.y == e);
    bool f = f1 || f2;
    unsigned long long m = __ballot(f);
    int rank = __popcll(m & ((1ull << l) - 1ull));
    if (l == 0) wsum[w] = __popcll(m);
    __syncthreads();
    int woff = 0;
#pragma unroll
    for (int i = 0; i < 4; ++i) if (i < w) woff += wsum[i];
    int tot = wsum[0] + wsum[1] + wsum[2] + wsum[3];
    int pos = base + woff + rank;
    if (f && pos < CAP) {
      dispatch[e * CAP + pos] = t;
      sgate[e * CAP + pos] = f1 ? tg.x : tg.y;
    }
    base += tot;
    __syncthreads();
  }
  int start = base < CAP ? base : CAP;
  for (int p = start + tid; p < CAP; p += 256) {
    dispatch[e * CAP + p] = T_TOK;
    sgate[e * CAP + p] = 0.f;
  }
  if (tid == 0) cnt[e] = base < CAP ? base : CAP;
}

// ---------------- transpose + fp32->bf16: (K,N) -> (N,K), 64x64 tiles -------
__global__ __launch_bounds__(256) void transpose_kernel(
    const float* __restrict__ src, unsigned short* __restrict__ dst,
    int K, int N)
{
  const float* s = src + (size_t)blockIdx.z * K * N;
  unsigned short* d = dst + (size_t)blockIdx.z * K * N;
  __shared__ float tile[64][65];
  int n0 = blockIdx.x * 64;
  int k0 = blockIdx.y * 64;
  int tid = threadIdx.x;
  int r = tid >> 4;           // 0..15
  int c4 = (tid & 15) * 4;
#pragma unroll
  for (int i = 0; i < 4; ++i) {
    int row = r + i * 16;
    float4 v = *(const float4*)&s[(size_t)(k0 + row) * N + n0 + c4];
    tile[row][c4] = v.x; tile[row][c4 + 1] = v.y;
    tile[row][c4 + 2] = v.z; tile[row][c4 + 3] = v.w;
  }
  __syncthreads();
  int n = tid >> 2;           // 0..63
  int kg = tid & 3;
#pragma unroll
  for (int j = 0; j < 2; ++j) {
    int kc = kg * 2 + j;      // 0..7
    u16x8 o;
#pragma unroll
    for (int q = 0; q < 8; ++q) o[q] = f2bf(tile[kc * 8 + q][n]);
    *(u16x8*)&d[(size_t)(n0 + n) * K + k0 + kc * 8] = o;
  }
}

// LDS swizzle: tile unit u = row*4 + s (16B units, 32 bf16 per row)
// stored at u' = u ^ ((u>>3)&7); involution (key from XOR-invariant bits).
// Read (row, s=lhi): 16 lanes/lhi-group spread over all 8 16B-columns -> 2-way (free).

// ---------------- GEMM1: h = gelu(xg @ w1 + b1), h stored bf16 --------------
#define G1_NXB (F_DIM / 128)   // 32
__global__ __launch_bounds__(256, 3) void gemm1_kernel(
    const unsigned short* __restrict__ xbf,   // (T+1, D) bf16, row T zeroed
    const unsigned short* __restrict__ w1t,   // (F, D) bf16 per expert
    const float* __restrict__ b1,             // (E, F)
    const int* __restrict__ dispatch,         // (E, CAP)
    const int* __restrict__ cnt,              // (E)
    unsigned short* __restrict__ h,           // (CAP, F) bf16 per expert
    int e_base, size_t w1stride, size_t hstride)
{
  int wg = xcd_swizzle(blockIdx.x, gridDim.x);
  int my = wg % MYB;
  int p  = wg / MYB;
  int nx = p % G1_NXB;
  int ez = p / G1_NXB;
  int e = e_base + ez;
  int m0 = my * 128;
  if (m0 >= cnt[e]) return;   // whole M-block is padding
  const unsigned short* w1e = w1t + (size_t)ez * w1stride;
  unsigned short* he = h + (size_t)ez * hstride;
  int n0 = nx * 128;
  int tid = threadIdx.x;
  int l = tid & 63;
  int wid = tid >> 6;
  int wm = wid >> 1, wn = wid & 1;
  int lrow = l & 15, lhi = l >> 4;

  __shared__ __align__(16) char lds[3 * LDSB];

  // stage slots (per thread: 2 A-units + 2 B-units, 16B each)
  const unsigned short* ag[2];
  const unsigned short* bg[2];
  int ldsA[2], ldsB[2];
#pragma unroll
  for (int j = 0; j < 2; ++j) {
    int chunk = wid * 2 + j;            // 0..7 (wave-uniform)
    int U = chunk * 64 + l;             // linear LDS unit this lane writes
    int u = U ^ ((U >> 3) & 7);         // inverse swizzle -> tile coords
    int row = u >> 2, s = u & 3;
    int tok = dispatch[e * CAP + m0 + row];
    ag[j] = xbf + (size_t)tok * D_DIM + s * 8;
    bg[j] = w1e + (size_t)(n0 + row) * D_DIM + s * 8;
    ldsA[j] = chunk * 1024;
    ldsB[j] = 8192 + chunk * 1024;
  }

  // swizzled read offsets (bytes within buffer)
  int aoff[4], boff[4];
#pragma unroll
  for (int m = 0; m < 4; ++m) {
    int row = wm * 64 + m * 16 + lrow;
    int u = row * 4 + lhi;
    aoff[m] = (u ^ ((row >> 1) & 7)) * 16;
    int colr = wn * 64 + m * 16 + lrow;
    int ub = colr * 4 + lhi;
    boff[m] = 8192 + (ub ^ ((colr >> 1) & 7)) * 16;
  }

  f32x4 acc[4][4];
#pragma unroll
  for (int m = 0; m < 4; ++m)
#pragma unroll
    for (int n = 0; n < 4; ++n) acc[m][n] = (f32x4){0.f, 0.f, 0.f, 0.f};

#define STAGE1(BASE, KOFF) do { \
    __builtin_amdgcn_global_load_lds((gas_ptr)(ag[0] + (KOFF)), (las_ptr)(lds + (BASE) + ldsA[0]), 16, 0, 0); \
    __builtin_amdgcn_global_load_lds((gas_ptr)(bg[0] + (KOFF)), (las_ptr)(lds + (BASE) + ldsB[0]), 16, 0, 0); \
    __builtin_amdgcn_global_load_lds((gas_ptr)(ag[1] + (KOFF)), (las_ptr)(lds + (BASE) + ldsA[1]), 16, 0, 0); \
    __builtin_amdgcn_global_load_lds((gas_ptr)(bg[1] + (KOFF)), (las_ptr)(lds + (BASE) + ldsB[1]), 16, 0, 0); \
  } while (0)

  const int NT = D_DIM / BKS;   // 32
  STAGE1(0, 0);
  STAGE1(LDSB, BKS);
  PIPE_BAR4();                  // buf0 globally ready; buf1 (4 loads) in flight

  int cb = 0, sb = 2 * LDSB, koff = 2 * BKS;
  for (int t = 0; t < NT; ++t) {
    if (t + 2 < NT) { STAGE1(sb, koff); koff += BKS; }
    bf16x8 af[4], bfr[4];
#pragma unroll
    for (int m = 0; m < 4; ++m) af[m] = *(const bf16x8*)(lds + cb + aoff[m]);
#pragma unroll
    for (int n = 0; n < 4; ++n) bfr[n] = *(const bf16x8*)(lds + cb + boff[n]);
    __builtin_amdgcn_s_setprio(1);
#pragma unroll
    for (int m = 0; m < 4; ++m)
#pragma unroll
      for (int n = 0; n < 4; ++n)
        acc[m][n] = __builtin_amdgcn_mfma_f32_16x16x32_bf16(af[m], bfr[n], acc[m][n], 0, 0, 0);
    __builtin_amdgcn_s_setprio(0);
    if (t + 1 < NT) {
      if (t + 2 < NT) PIPE_BAR4(); else PIPE_BAR0();
      cb = (cb == 2 * LDSB) ? 0 : cb + LDSB;
      sb = (sb == 2 * LDSB) ? 0 : sb + LDSB;
    }
  }

  int colg[4]; float b1v[4];
#pragma unroll
  for (int n = 0; n < 4; ++n) {
    colg[n] = n0 + wn * 64 + n * 16 + lrow;
    b1v[n] = b1[e * F_DIM + colg[n]];
  }
#pragma unroll
  for (int m = 0; m < 4; ++m) {
    int rb = m0 + wm * 64 + m * 16 + lhi * 4;
#pragma unroll
    for (int j = 0; j < 4; ++j) {
      int r = rb + j;
      unsigned short* hr = he + (size_t)r * F_DIM;
#pragma unroll
      for (int n = 0; n < 4; ++n) {
        float v = acc[m][n][j] + b1v[n];
        hr[colg[n]] = f2bf(gelu_f(v));
      }
    }
  }
}

// ---------------- GEMM2: y = h @ w2 + b2; out[tok] += gate*y (atomic) -------
#define G2_NXB (D_DIM / 128)   // 8
__global__ __launch_bounds__(256, 3) void gemm2_kernel(
    const unsigned short* __restrict__ h,     // (CAP, F) bf16 per expert
    const unsigned short* __restrict__ w2t,   // (D, F) bf16 per expert
    const float* __restrict__ b2,             // (E, D)
    const int* __restrict__ dispatch,
    const float* __restrict__ sgate,
    const int* __restrict__ cnt,
    float* __restrict__ out,                  // (T, D) fp32, zero-initialized
    int e_base, size_t w2stride, size_t hstride)
{
  int wg = xcd_swizzle(blockIdx.x, gridDim.x);
  int my = wg % MYB;
  int p  = wg / MYB;
  int nx = p % G2_NXB;
  int ez = p / G2_NXB;
  int e = e_base + ez;
  int m0 = my * 128;
  if (m0 >= cnt[e]) return;
  const unsigned short* he = h + (size_t)ez * hstride;
  const unsigned short* w2e = w2t + (size_t)ez * w2stride;
  int n0 = nx * 128;
  int tid = threadIdx.x;
  int l = tid & 63;
  int wid = tid >> 6;
  int wm = wid >> 1, wn = wid & 1;
  int lrow = l & 15, lhi = l >> 4;

  __shared__ __align__(16) char lds[3 * LDSB];

  const unsigned short* ag[2];
  const unsigned short* bg[2];
  int ldsA[2], ldsB[2];
#pragma unroll
  for (int j = 0; j < 2; ++j) {
    int chunk = wid * 2 + j;
    int U = chunk * 64 + l;
    int u = U ^ ((U >> 3) & 7);
    int row = u >> 2, s = u & 3;
    ag[j] = he + (size_t)(m0 + row) * F_DIM + s * 8;
    bg[j] = w2e + (size_t)(n0 + row) * F_DIM + s * 8;
    ldsA[j] = chunk * 1024;
    ldsB[j] = 8192 + chunk * 1024;
  }

  int aoff[4], boff[4];
#pragma unroll
  for (int m = 0; m < 4; ++m) {
    int row = wm * 64 + m * 16 + lrow;
    int u = row * 4 + lhi;
    aoff[m] = (u ^ ((row >> 1) & 7)) * 16;
    int colr = wn * 64 + m * 16 + lrow;
    int ub = colr * 4 + lhi;
    boff[m] = 8192 + (ub ^ ((colr >> 1) & 7)) * 16;
  }

  f32x4 acc[4][4];
#pragma unroll
  for (int m = 0; m < 4; ++m)
#pragma unroll
    for (int n = 0; n < 4; ++n) acc[m][n] = (f32x4){0.f, 0.f, 0.f, 0.f};

#define STAGE2(BASE, KOFF) do { \
    __builtin_amdgcn_global_load_lds((gas_ptr)(ag[0] + (KOFF)), (las_ptr)(lds + (BASE) + ldsA[0]), 16, 0, 0); \
    __builtin_amdgcn_global_load_lds((gas_ptr)(bg[0] + (KOFF)), (las_ptr)(lds + (BASE) + ldsB[0]), 16, 0, 0); \
    __builtin_amdgcn_global_load_lds((gas_ptr)(ag[1] + (KOFF)), (las_ptr)(lds + (BASE) + ldsA[1]), 16, 0, 0); \
    __builtin_amdgcn_global_load_lds((gas_ptr)(bg[1] + (KOFF)), (las_ptr)(lds + (BASE) + ldsB[1]), 16, 0, 0); \
  } while (0)

  const int NT = F_DIM / BKS;   // 128
  STAGE2(0, 0);
  STAGE2(LDSB, BKS);
  PIPE_BAR4();

  int cb = 0, sb = 2 * LDSB, koff = 2 * BKS;
  for (int t = 0; t < NT; ++t) {
    if (t + 2 < NT) { STAGE2(sb, koff); koff += BKS; }
    bf16x8 af[4], bfr[4];
#pragma unroll
    for (int m = 0; m < 4; ++m) af[m] = *(const bf16x8*)(lds + cb + aoff[m]);
#pragma unroll
    for (int n = 0; n < 4; ++n) bfr[n] = *(const bf16x8*)(lds + cb + boff[n]);
    __builtin_amdgcn_s_setprio(1);
#pragma unroll
    for (int m = 0; m < 4; ++m)
#pragma unroll
      for (int n = 0; n < 4; ++n)
        acc[m][n] = __builtin_amdgcn_mfma_f32_16x16x32_bf16(af[m], bfr[n], acc[m][n], 0, 0, 0);
    __builtin_amdgcn_s_setprio(0);
    if (t + 1 < NT) {
      if (t + 2 < NT) PIPE_BAR4(); else PIPE_BAR0();
      cb = (cb == 2 * LDSB) ? 0 : cb + LDSB;
      sb = (sb == 2 * LDSB) ? 0 : sb + LDSB;
    }
  }

  int colg[4]; float b2v[4];
#pragma unroll
  for (int n = 0; n < 4; ++n) {
    colg[n] = n0 + wn * 64 + n * 16 + lrow;
    b2v[n] = b2[e * D_DIM + colg[n]];
  }
#pragma unroll
  for (int m = 0; m < 4; ++m) {
    int rb = m0 + wm * 64 + m * 16 + lhi * 4;
#pragma unroll
    for (int j = 0; j < 4; ++j) {
      int r = rb + j;
      int tok = dispatch[e * CAP + r];
      if (tok < T_TOK) {
        float g = sgate[e * CAP + r];
        float* orow = out + (size_t)tok * D_DIM;
#pragma unroll
        for (int n = 0; n < 4; ++n)
          atomicAdd(&orow[colg[n]], g * (acc[m][n][j] + b2v[n]));
      }
    }
  }
}

// ---------------- host-side launch ------------------------------------------
extern "C" void kernel_launch(void* const* d_in, const int* in_sizes, int n_in,
                              void* d_out, int out_size, void* d_ws, size_t ws_size,
                              hipStream_t stream) {
  const float* x  = (const float*)d_in[0];
  const float* wr = (const float*)d_in[1];
  const float* w1 = (const float*)d_in[2];
  const float* b1 = (const float*)d_in[3];
  const float* w2 = (const float*)d_in[4];
  const float* b2 = (const float*)d_in[5];
  float* out = (float*)d_out;

  char* ws = (char*)d_ws;
  size_t off = 0;
  auto alloc = [&](size_t bytes) -> void* {
    off = (off + 255) & ~(size_t)255;
    void* p = ws + off;
    off += bytes;
    return p;
  };
  int*   dispatch = (int*)alloc((size_t)E_NUM * CAP * 4);
  float* sgate    = (float*)alloc((size_t)E_NUM * CAP * 4);
  int*   cnt      = (int*)alloc((size_t)E_NUM * 4);
  int2*  tokE     = (int2*)alloc((size_t)T_TOK * 8);
  float2* tokG    = (float2*)alloc((size_t)T_TOK * 8);
  unsigned short* xbf = (unsigned short*)alloc((size_t)(T_TOK + 1) * D_DIM * 2);

  const size_t wsz = (size_t)D_DIM * F_DIM * 2;  // one expert weight, bf16 bytes
  const size_t hsz = (size_t)CAP * F_DIM * 2;    // one expert h, bf16 bytes
  size_t remain = ws_size > off ? ws_size - off : 0;
  bool tierA = remain >= (size_t)E_NUM * (2 * wsz + hsz) + (size_t)(1 << 16);

  hipMemsetAsync(out, 0, (size_t)T_TOK * D_DIM * 4, stream);
  hipMemsetAsync(xbf + (size_t)T_TOK * D_DIM, 0, D_DIM * 2, stream);
  route_kernel<<<T_TOK / 4, 256, 0, stream>>>(x, wr, xbf, tokE, tokG);
  scan_kernel<<<E_NUM, 256, 0, stream>>>(tokE, tokG, dispatch, sgate, cnt);

  if (tierA) {
    unsigned short* w1t = (unsigned short*)alloc((size_t)E_NUM * wsz);
    unsigned short* w2t = (unsigned short*)alloc((size_t)E_NUM * wsz);
    unsigned short* hb  = (unsigned short*)alloc((size_t)E_NUM * hsz);
    transpose_kernel<<<dim3(F_DIM / 64, D_DIM / 64, E_NUM), 256, 0, stream>>>(w1, w1t, D_DIM, F_DIM);
    transpose_kernel<<<dim3(D_DIM / 64, F_DIM / 64, E_NUM), 256, 0, stream>>>(w2, w2t, F_DIM, D_DIM);
    gemm1_kernel<<<dim3(G1_NXB * MYB * E_NUM), 256, 0, stream>>>(
        xbf, w1t, b1, dispatch, cnt, hb, 0, wsz / 2, hsz / 2);
    gemm2_kernel<<<dim3(G2_NXB * MYB * E_NUM), 256, 0, stream>>>(
        hb, w2t, b2, dispatch, sgate, cnt, out, 0, wsz / 2, hsz / 2);
  } else {
    unsigned short* w1t = (unsigned short*)alloc(wsz);
    unsigned short* w2t = (unsigned short*)alloc(wsz);
    unsigned short* hb  = (unsigned short*)alloc(hsz);
    for (int e = 0; e < E_NUM; ++e) {
      transpose_kernel<<<dim3(F_DIM / 64, D_DIM / 64, 1), 256, 0, stream>>>(
          w1 + (size_t)e * D_DIM * F_DIM, w1t, D_DIM, F_DIM);
      gemm1_kernel<<<dim3(G1_NXB * MYB), 256, 0, stream>>>(
          xbf, w1t, b1, dispatch, cnt, hb, e, 0, 0);
      transpose_kernel<<<dim3(D_DIM / 64, F_DIM / 64, 1), 256, 0, stream>>>(
          w2 + (size_t)e * D_DIM * F_DIM, w2t, F_DIM, D_DIM);
      gemm2_kernel<<<dim3(G2_NXB * MYB), 256, 0, stream>>>(
          hb, w2t, b2, dispatch, sgate, cnt, out, e, 0, 0);
    }
  }
}